// Round 8
// baseline (122.723 us; speedup 1.0000x reference)
//
#include <hip/hip_runtime.h>
#include <hip/hip_bf16.h>
#include <math.h>

#define BT 48
#define N 1024
#define F 64
#define CIN 64
#define EM 16
#define LRELU_A 0.2f
#define L2E 1.4426950408889634f

typedef short bf16x8 __attribute__((ext_vector_type(8)));   // 8 bf16 = 4 VGPRs
typedef float f32x4  __attribute__((ext_vector_type(4)));
typedef unsigned int u32x4 __attribute__((ext_vector_type(4)));

// exact RTNE float->bf16 bits (k_proj only, off hot path)
__device__ __forceinline__ unsigned short f2bf(float f) {
    unsigned int u = __float_as_uint(f);
    return (unsigned short)((u + 0x7FFFu + ((u >> 16) & 1u)) >> 16);
}

// ------------------------------------------------------------------
// k_proj_misc (unchanged, LDS sx staging)
// ------------------------------------------------------------------
__global__ __launch_bounds__(256) void k_proj_misc(
    const float* __restrict__ x, const float* __restrict__ W,
    const float* __restrict__ a,
    const int* __restrict__ adj,
    const float* __restrict__ emb1, const float* __restrict__ emb2,
    const float* __restrict__ a2,
    unsigned short* __restrict__ WhSw,
    float* __restrict__ s1, float* __restrict__ s2,
    unsigned int* __restrict__ adjBits,
    float* __restrict__ f1, float* __restrict__ f2)
{
    const int tid = threadIdx.x;
    const int b   = blockIdx.x;

    __shared__ __align__(16) float sx[64 * 64];
    __shared__ __align__(16) float sWT[64 * 68];
    __shared__ __align__(16) unsigned short sT[64 * 80];

    const int bt  = b >> 4;
    const int n0  = (b & 15) * 64;
    const size_t grow = (size_t)bt * N + n0;

    {
        const float4* xv = (const float4*)(x + grow * CIN);
        float4* sxv = (float4*)sx;
        for (int i = tid; i < 64 * CIN / 4; i += 256) sxv[i] = xv[i];
        for (int i = tid; i < CIN * F; i += 256)
            sWT[(i & 63) * 68 + (i >> 6)] = W[i];
    }
    __syncthreads();

    const int f = tid & 63;
    const int w = tid >> 6;
    const float a1 = a[f], a2c = a[F + f];

    float acc[16];
#pragma unroll
    for (int t = 0; t < 16; ++t) acc[t] = 0.f;

    for (int cb = 0; cb < CIN; cb += 4) {
        const float4 wv = *(const float4*)&sWT[f * 68 + cb];
#pragma unroll
        for (int t = 0; t < 16; ++t) {
            const float4 xv = *(const float4*)&sx[(w * 16 + t) * 64 + cb];
            acc[t] = fmaf(xv.x, wv.x, acc[t]);
            acc[t] = fmaf(xv.y, wv.y, acc[t]);
            acc[t] = fmaf(xv.z, wv.z, acc[t]);
            acc[t] = fmaf(xv.w, wv.w, acc[t]);
        }
    }

#pragma unroll
    for (int t = 0; t < 16; ++t) {
        float v1 = acc[t] * a1;
        float v2 = acc[t] * a2c;
#pragma unroll
        for (int off = 32; off >= 1; off >>= 1) {
            v1 += __shfl_xor(v1, off, 64);
            v2 += __shfl_xor(v2, off, 64);
        }
        if (f == 0) {
            s1[grow + w * 16 + t] = v1;
            s2[grow + w * 16 + t] = v2;
        }
        sT[f * 80 + w * 16 + t] = f2bf(acc[t]);
    }
    __syncthreads();

    {
        const int ff = tid >> 2, q = tid & 3;
        const int slot = (q + ff) & 3;
        const int nb0 = (b & 15) * 2;
#pragma unroll
        for (int nbL = 0; nbL < 2; ++nbL) {
            const size_t dst = ((size_t)(bt * 32 + nb0 + nbL) * 64 + ff) * 32 + slot * 8;
            *(uint4*)&WhSw[dst] = *(const uint4*)&sT[ff * 80 + nbL * 32 + q * 8];
        }
    }

    if (b < 128) {
        const int idx = b * 256 + tid;
        const int r = idx >> 5, w32 = idx & 31;
        const int* p = adj + (size_t)r * N + w32 * 32;
        unsigned int m = 0;
#pragma unroll
        for (int j = 0; j < 32; ++j) m |= (p[j] > 0 ? 1u : 0u) << j;
        adjBits[idx] = m;
    } else if (b < 132) {
        const int n = (b - 128) * 256 + tid;
        float v1 = 0.f, v2 = 0.f;
#pragma unroll
        for (int k = 0; k < EM; ++k) {
            v1 = fmaf(emb1[n * EM + k], a2[k], v1);
            v2 = fmaf(emb2[n * EM + k], a2[EM + k], v2);
        }
        f1[n] = v1; f2[n] = v2;
    }
}

// ------------------------------------------------------------------
// k_attn round 15 "ksplit": waves split the K dimension, not rows.
// Wave w covers ALL 64 rows x chunks {2w,2w+1} (256 k-cols), partial
// acc[4 row-groups][4 ct]. B-fragments read DIRECTLY from global
// (L2-resident; each B element read once per block vs 4x before; 16
// named bb regs = forced prefetch depth, PAIR VALU covers latency).
// ZERO main-loop barriers. LDS ops/thread: 256 -> ~64 (4x cut of the
// measured bottleneck). Cross-wave f32 reduction via sAcc at the end.
// ------------------------------------------------------------------

#define PAIRG(g, x1e, x1o, x2e, x2o, bit, dest) do {                       \
    const bool s0_ = (x1e) > T##g;                                         \
    const bool s1_ = (x1o) > T##g;                                         \
    float p0_ = (s0_ ? (x1e) : (x2e)) * (s0_ ? E1##g : E2##g);             \
    float p1_ = (s1_ ? (x1o) : (x2o)) * (s1_ ? E1##g : E2##g);             \
    p0_ = ((mb_ >> (bit)) & 1u) ? p0_ : 0.f;                               \
    p1_ = ((mb_ >> ((bit) + 1)) & 1u) ? p1_ : 0.f;                         \
    lsum##g += p0_ + p1_;                                                  \
    dest = __builtin_amdgcn_perm(__float_as_uint(p1_) + 0x8000u,           \
                                 __float_as_uint(p0_) + 0x8000u,           \
                                 0x07060302u);                             \
} while (0)

#define MAKE_ONEG(ch, ks, g, Avar, abword) do {                            \
    const int jb_ = (ch) * 128 + (ks) * 32 + q * 8;                        \
    const float4 x1a_ = *(const float4*)&sX1[jb_];                         \
    const float4 x1b_ = *(const float4*)&sX1[jb_ + 4];                     \
    const float4 x2a_ = *(const float4*)&sX2[jb_];                         \
    const float4 x2b_ = *(const float4*)&sX2[jb_ + 4];                     \
    const unsigned int mb_ = ((abword) >> (q * 8)) & 0xFFu;                \
    unsigned int u0_, u1_, u2_, u3_;                                       \
    PAIRG(g, x1a_.x, x1a_.y, x2a_.x, x2a_.y, 0, u0_);                      \
    PAIRG(g, x1a_.z, x1a_.w, x2a_.z, x2a_.w, 2, u1_);                      \
    PAIRG(g, x1b_.x, x1b_.y, x2b_.x, x2b_.y, 4, u2_);                      \
    PAIRG(g, x1b_.z, x1b_.w, x2b_.z, x2b_.w, 6, u3_);                      \
    u32x4 av_; av_.x = u0_; av_.y = u1_; av_.z = u2_; av_.w = u3_;         \
    Avar = __builtin_bit_cast(bf16x8, av_);                                \
} while (0)

#define MFMA(g, ct, Af, Bf)                                                \
    acc##g##_##ct = __builtin_amdgcn_mfma_f32_16x16x32_bf16(               \
        Af, Bf, acc##g##_##ct, 0, 0, 0)

// all 64 rows for chunk ch: 4 row-groups, B-frags shared across groups
#define GBODY(g, ch) do {                                                  \
    const uint4 abv_ = *(const uint4*)(abRow##g + (ch) * 4);               \
    bf16x8 fa0_, fa1_, fa2_, fa3_;                                         \
    MAKE_ONEG(ch, 0, g, fa0_, abv_.x);                                     \
    MAKE_ONEG(ch, 1, g, fa1_, abv_.y);                                     \
    MAKE_ONEG(ch, 2, g, fa2_, abv_.z);                                     \
    MAKE_ONEG(ch, 3, g, fa3_, abv_.w);                                     \
    MFMA(g, 0, fa0_, bb00); MFMA(g, 0, fa1_, bb10);                        \
    MFMA(g, 0, fa2_, bb20); MFMA(g, 0, fa3_, bb30);                        \
    MFMA(g, 1, fa0_, bb01); MFMA(g, 1, fa1_, bb11);                        \
    MFMA(g, 1, fa2_, bb21); MFMA(g, 1, fa3_, bb31);                        \
    MFMA(g, 2, fa0_, bb02); MFMA(g, 2, fa1_, bb12);                        \
    MFMA(g, 2, fa2_, bb22); MFMA(g, 2, fa3_, bb32);                        \
    MFMA(g, 3, fa0_, bb03); MFMA(g, 3, fa1_, bb13);                        \
    MFMA(g, 3, fa2_, bb23); MFMA(g, 3, fa3_, bb33);                        \
} while (0)

#define LOADB(ks, ct)                                                      \
    bb##ks##ct = *(const bf16x8*)(gBc + (size_t)ch_ * 16384 +              \
                 (ks) * 4096 + ((ct) * 16 + m15) * 64 + slotoff)

#define CHUNK(ch) do { const int ch_ = (ch);                               \
    LOADB(0,0); LOADB(1,0); LOADB(2,0); LOADB(3,0);                        \
    LOADB(0,1); LOADB(1,1); LOADB(2,1); LOADB(3,1);                        \
    LOADB(0,2); LOADB(1,2); LOADB(2,2); LOADB(3,2);                        \
    LOADB(0,3); LOADB(1,3); LOADB(2,3); LOADB(3,3);                        \
    GBODY(0, ch_); GBODY(1, ch_); GBODY(2, ch_); GBODY(3, ch_);            \
} while (0)

#define ROWPARM(g) \
    const int row##g = i0 + (g) * 16 + m15;                                \
    const float rr##g = (s1[bt * N + row##g] + f1v[row##g]) * L2E;         \
    const float smx##g = rr##g + mx;                                       \
    const float mh##g = fmaxf(smx##g, LRELU_A * smx##g);                   \
    const float E1##g = exp2f(rr##g - mh##g);                              \
    const float E2##g = exp2f(LRELU_A * rr##g - mh##g);                    \
    const float T##g  = exp2f(-rr##g);                                     \
    float lsum##g = 0.f;                                                   \
    const unsigned int* abRow##g = adjBits + (size_t)row##g * 32

#define STACC(g, ct)                                                       \
    *(f32x4*)&sAcc[((w * 4 + (g)) * 1024) + (ct) * 256 + lane * 4] =       \
        acc##g##_##ct

#define RDACC(ct)                                                          \
    f32x4 sum##ct;                                                         \
    {                                                                      \
        f32x4 s0_ = *(const f32x4*)&sAcc[(0 * 4 + w) * 1024 + (ct) * 256 + lane * 4]; \
        f32x4 s1_ = *(const f32x4*)&sAcc[(1 * 4 + w) * 1024 + (ct) * 256 + lane * 4]; \
        f32x4 s2_ = *(const f32x4*)&sAcc[(2 * 4 + w) * 1024 + (ct) * 256 + lane * 4]; \
        f32x4 s3_ = *(const f32x4*)&sAcc[(3 * 4 + w) * 1024 + (ct) * 256 + lane * 4]; \
        sum##ct = (s0_ + s1_) + (s2_ + s3_);                               \
    }

#define EPI(ct, accv) do {                                                 \
    float h0_ = accv.x * rinv0, h1_ = accv.y * rinv1,                      \
          h2_ = accv.z * rinv2, h3_ = accv.w * rinv3;                      \
    h0_ = (h0_ > 0.f) ? h0_ : (__expf(h0_) - 1.f);                         \
    h1_ = (h1_ > 0.f) ? h1_ : (__expf(h1_) - 1.f);                         \
    h2_ = (h2_ > 0.f) ? h2_ : (__expf(h2_) - 1.f);                         \
    h3_ = (h3_ > 0.f) ? h3_ : (__expf(h3_) - 1.f);                         \
    float* op_ = out + (size_t)(bt * N + i0 + w * 16 + q * 4) * F          \
                 + (ct) * 16 + m15;                                        \
    op_[0 * F] = h0_; op_[1 * F] = h1_; op_[2 * F] = h2_; op_[3 * F] = h3_;\
} while (0)

__global__ __launch_bounds__(256, 2) void k_attn(
    const unsigned int* __restrict__ adjBits,
    const unsigned short* __restrict__ WhSw,
    const float* __restrict__ s1, const float* __restrict__ s2,
    const float* __restrict__ f1v, const float* __restrict__ f2v,
    float* __restrict__ out)
{
    __shared__ __align__(16) float sX1[N];                  // 2^c   (scaled domain)
    __shared__ __align__(16) float sX2[N];                  // 2^.2c
    __shared__ __align__(16) float sAcc[16 * 1024];         // 64 KB partials
    __shared__ __align__(16) float sLsum[256];
    __shared__ float sWmax[4];

    const int tid  = threadIdx.x;
    const int xcd = blockIdx.x & 7;                         // XCD swizzle: 6 bt/XCD
    const int idx = blockIdx.x >> 3;
    const int bt  = xcd * 6 + (idx >> 4);
    const int i0  = (idx & 15) * 64;
    const int lane = tid & 63;
    const int w    = tid >> 6;
    const int q    = lane >> 4;
    const int m15  = lane & 15;

    // stage X1/X2 and track block max of c (scaled by log2e)
    float cmax = -1e30f;
    for (int j = tid; j < N; j += 256) {
        const float c = (s2[bt * N + j] + f2v[j]) * L2E;
        sX1[j] = exp2f(c);
        sX2[j] = exp2f(LRELU_A * c);
        cmax = fmaxf(cmax, c);
    }
#pragma unroll
    for (int off = 32; off >= 1; off >>= 1) cmax = fmaxf(cmax, __shfl_xor(cmax, off, 64));
    if (lane == 0) sWmax[w] = cmax;
    __syncthreads();
    const float mx = fmaxf(fmaxf(sWmax[0], sWmax[1]), fmaxf(sWmax[2], sWmax[3]));

    // per-row-group params (this wave covers ALL 64 rows of the block)
    ROWPARM(0); ROWPARM(1); ROWPARM(2); ROWPARM(3);

    const char* gBc = (const char*)(WhSw + (size_t)bt * 65536);
    const int slotoff = ((q + m15) & 3) * 16;               // XOR-swizzled slot

    f32x4 acc0_0 = 0.f, acc0_1 = 0.f, acc0_2 = 0.f, acc0_3 = 0.f;
    f32x4 acc1_0 = 0.f, acc1_1 = 0.f, acc1_2 = 0.f, acc1_3 = 0.f;
    f32x4 acc2_0 = 0.f, acc2_1 = 0.f, acc2_2 = 0.f, acc2_3 = 0.f;
    f32x4 acc3_0 = 0.f, acc3_1 = 0.f, acc3_2 = 0.f, acc3_3 = 0.f;
    bf16x8 bb00, bb01, bb02, bb03, bb10, bb11, bb12, bb13;
    bf16x8 bb20, bb21, bb22, bb23, bb30, bb31, bb32, bb33;

    // barrier-free main loop: this wave's two chunks only
    CHUNK(2 * w);
    CHUNK(2 * w + 1);

    // within-wave q-reduction of row sums
    lsum0 += __shfl_xor(lsum0, 16, 64); lsum0 += __shfl_xor(lsum0, 32, 64);
    lsum1 += __shfl_xor(lsum1, 16, 64); lsum1 += __shfl_xor(lsum1, 32, 64);
    lsum2 += __shfl_xor(lsum2, 16, 64); lsum2 += __shfl_xor(lsum2, 32, 64);
    lsum3 += __shfl_xor(lsum3, 16, 64); lsum3 += __shfl_xor(lsum3, 32, 64);
    if (q == 0) {
        sLsum[w * 64 +  0 + m15] = lsum0;
        sLsum[w * 64 + 16 + m15] = lsum1;
        sLsum[w * 64 + 32 + m15] = lsum2;
        sLsum[w * 64 + 48 + m15] = lsum3;
    }

    STACC(0, 0); STACC(0, 1); STACC(0, 2); STACC(0, 3);
    STACC(1, 0); STACC(1, 1); STACC(1, 2); STACC(1, 3);
    STACC(2, 0); STACC(2, 1); STACC(2, 2); STACC(2, 3);
    STACC(3, 0); STACC(3, 1); STACC(3, 2); STACC(3, 3);
    __syncthreads();

    // each wave reduces its own row-quarter (g == w) across the 4 k-partials
    RDACC(0); RDACC(1); RDACC(2); RDACC(3);

    f32x4 rsum;
    {
        f32x4 l0 = *(const f32x4*)&sLsum[0 * 64 + w * 16 + q * 4];
        f32x4 l1 = *(const f32x4*)&sLsum[1 * 64 + w * 16 + q * 4];
        f32x4 l2 = *(const f32x4*)&sLsum[2 * 64 + w * 16 + q * 4];
        f32x4 l3 = *(const f32x4*)&sLsum[3 * 64 + w * 16 + q * 4];
        rsum = (l0 + l1) + (l2 + l3);
    }
    const float rinv0 = 1.f / rsum.x;
    const float rinv1 = 1.f / rsum.y;
    const float rinv2 = 1.f / rsum.z;
    const float rinv3 = 1.f / rsum.w;

    EPI(0, sum0); EPI(1, sum1); EPI(2, sum2); EPI(3, sum3);
}

// ------------------------------------------------------------------
extern "C" void kernel_launch(void* const* d_in, const int* in_sizes, int n_in,
                              void* d_out, int out_size, void* d_ws, size_t ws_size,
                              hipStream_t stream)
{
    const float* x    = (const float*)d_in[0];
    const int*   adj  = (const int*)  d_in[1];
    const float* emb1 = (const float*)d_in[2];
    const float* emb2 = (const float*)d_in[3];
    const float* W    = (const float*)d_in[4];
    const float* a    = (const float*)d_in[5];
    const float* a2   = (const float*)d_in[6];
    float* out = (float*)d_out;

    unsigned short* WhSw = (unsigned short*)d_ws;             // 6.29 MB
    float* s1 = (float*)(WhSw + (size_t)BT * 65536);
    float* s2 = s1 + BT * N;
    float* f1 = s2 + BT * N;
    float* f2 = f1 + N;
    unsigned int* adjBits = (unsigned int*)(f2 + N);          // 128 KB

    hipLaunchKernelGGL(k_proj_misc, dim3(768), dim3(256), 0, stream,
                       x, W, a, adj, emb1, emb2, a2, WhSw, s1, s2, adjBits, f1, f2);
    hipLaunchKernelGGL(k_attn, dim3(BT * 16), dim3(256), 0, stream,
                       adjBits, WhSw, s1, s2, f1, f2, out);
}

// Round 10
// 117.385 us; speedup vs baseline: 1.0455x; 1.0455x over previous
//
#include <hip/hip_runtime.h>
#include <hip/hip_bf16.h>
#include <math.h>

#define BT 48
#define N 1024
#define F 64
#define CIN 64
#define EM 16
#define LRELU_A 0.2f
#define L2E 1.4426950408889634f

typedef short bf16x8 __attribute__((ext_vector_type(8)));   // 8 bf16 = 4 VGPRs
typedef float f32x4  __attribute__((ext_vector_type(4)));
typedef unsigned int u32x4 __attribute__((ext_vector_type(4)));

// exact RTNE float->bf16 bits (k_proj only, off hot path)
__device__ __forceinline__ unsigned short f2bf(float f) {
    unsigned int u = __float_as_uint(f);
    return (unsigned short)((u + 0x7FFFu + ((u >> 16) & 1u)) >> 16);
}

// ------------------------------------------------------------------
// k_proj_misc (unchanged, LDS sx staging)
// ------------------------------------------------------------------
__global__ __launch_bounds__(256) void k_proj_misc(
    const float* __restrict__ x, const float* __restrict__ W,
    const float* __restrict__ a,
    const int* __restrict__ adj,
    const float* __restrict__ emb1, const float* __restrict__ emb2,
    const float* __restrict__ a2,
    unsigned short* __restrict__ WhSw,
    float* __restrict__ s1, float* __restrict__ s2,
    unsigned int* __restrict__ adjBits,
    float* __restrict__ f1, float* __restrict__ f2)
{
    const int tid = threadIdx.x;
    const int b   = blockIdx.x;

    __shared__ __align__(16) float sx[64 * 64];
    __shared__ __align__(16) float sWT[64 * 68];
    __shared__ __align__(16) unsigned short sT[64 * 80];

    const int bt  = b >> 4;
    const int n0  = (b & 15) * 64;
    const size_t grow = (size_t)bt * N + n0;

    {
        const float4* xv = (const float4*)(x + grow * CIN);
        float4* sxv = (float4*)sx;
        for (int i = tid; i < 64 * CIN / 4; i += 256) sxv[i] = xv[i];
        for (int i = tid; i < CIN * F; i += 256)
            sWT[(i & 63) * 68 + (i >> 6)] = W[i];
    }
    __syncthreads();

    const int f = tid & 63;
    const int w = tid >> 6;
    const float a1 = a[f], a2c = a[F + f];

    float acc[16];
#pragma unroll
    for (int t = 0; t < 16; ++t) acc[t] = 0.f;

    for (int cb = 0; cb < CIN; cb += 4) {
        const float4 wv = *(const float4*)&sWT[f * 68 + cb];
#pragma unroll
        for (int t = 0; t < 16; ++t) {
            const float4 xv = *(const float4*)&sx[(w * 16 + t) * 64 + cb];
            acc[t] = fmaf(xv.x, wv.x, acc[t]);
            acc[t] = fmaf(xv.y, wv.y, acc[t]);
            acc[t] = fmaf(xv.z, wv.z, acc[t]);
            acc[t] = fmaf(xv.w, wv.w, acc[t]);
        }
    }

#pragma unroll
    for (int t = 0; t < 16; ++t) {
        float v1 = acc[t] * a1;
        float v2 = acc[t] * a2c;
#pragma unroll
        for (int off = 32; off >= 1; off >>= 1) {
            v1 += __shfl_xor(v1, off, 64);
            v2 += __shfl_xor(v2, off, 64);
        }
        if (f == 0) {
            s1[grow + w * 16 + t] = v1;
            s2[grow + w * 16 + t] = v2;
        }
        sT[f * 80 + w * 16 + t] = f2bf(acc[t]);
    }
    __syncthreads();

    {
        const int ff = tid >> 2, q = tid & 3;
        const int slot = (q + ff) & 3;
        const int nb0 = (b & 15) * 2;
#pragma unroll
        for (int nbL = 0; nbL < 2; ++nbL) {
            const size_t dst = ((size_t)(bt * 32 + nb0 + nbL) * 64 + ff) * 32 + slot * 8;
            *(uint4*)&WhSw[dst] = *(const uint4*)&sT[ff * 80 + nbL * 32 + q * 8];
        }
    }

    if (b < 128) {
        const int idx = b * 256 + tid;
        const int r = idx >> 5, w32 = idx & 31;
        const int* p = adj + (size_t)r * N + w32 * 32;
        unsigned int m = 0;
#pragma unroll
        for (int j = 0; j < 32; ++j) m |= (p[j] > 0 ? 1u : 0u) << j;
        adjBits[idx] = m;
    } else if (b < 132) {
        const int n = (b - 128) * 256 + tid;
        float v1 = 0.f, v2 = 0.f;
#pragma unroll
        for (int k = 0; k < EM; ++k) {
            v1 = fmaf(emb1[n * EM + k], a2[k], v1);
            v2 = fmaf(emb2[n * EM + k], a2[EM + k], v2);
        }
        f1[n] = v1; f2[n] = v2;
    }
}

// ------------------------------------------------------------------
// k_attn round 16 "maxsel" (resubmitted): R7 counted-vmcnt structure,
// PAIR hot path shrunk via two exact rewrites:
//  1. LeakyReLU-in-exp-domain IS a max: 2^x monotone =>
//     p = 2^(LRelu(r+c)-mhat) = max(X1*E1, X2*E2).
//  2. bf16 pair pack via one v_cvt_pk_bf16_f32 (T12, gfx950-verified
//     inline-asm form) instead of 2x(+0x8000)+v_perm.
// PAIR: ~17 -> ~12 inst / 2 elems (-25% total kernel VALU).
// ------------------------------------------------------------------

#define WAIT_VM4 asm volatile("s_waitcnt vmcnt(4)" ::: "memory")
#define WAIT_VM0 asm volatile("s_waitcnt vmcnt(0)" ::: "memory")
#define BAR __builtin_amdgcn_s_barrier()

#define PAIR(x1e, x1o, x2e, x2o, bit, dest) do {                           \
    float p0_ = fmaxf((x1e) * E1, (x2e) * E2);                             \
    float p1_ = fmaxf((x1o) * E1, (x2o) * E2);                             \
    p0_ = ((mb_ >> (bit)) & 1u) ? p0_ : 0.f;                               \
    p1_ = ((mb_ >> ((bit) + 1)) & 1u) ? p1_ : 0.f;                         \
    lsum += p0_ + p1_;                                                     \
    unsigned int pk_;                                                      \
    asm("v_cvt_pk_bf16_f32 %0, %1, %2" : "=v"(pk_) : "v"(p0_), "v"(p1_)); \
    dest = pk_;                                                            \
} while (0)

// abword is a hoisted register (no VMEM here — only ds_read of sX + VALU)
#define MAKE_ONE(ch, ks, Avar, abword) do {                                \
    const int jb_ = (ch) * 128 + (ks) * 32 + q * 8;                        \
    const float4 x1a_ = *(const float4*)&sX1[jb_];                         \
    const float4 x1b_ = *(const float4*)&sX1[jb_ + 4];                     \
    const float4 x2a_ = *(const float4*)&sX2[jb_];                         \
    const float4 x2b_ = *(const float4*)&sX2[jb_ + 4];                     \
    const unsigned int mb_ = ((abword) >> (q * 8)) & 0xFFu;                \
    unsigned int u0_, u1_, u2_, u3_;                                       \
    PAIR(x1a_.x, x1a_.y, x2a_.x, x2a_.y, 0, u0_);                          \
    PAIR(x1a_.z, x1a_.w, x2a_.z, x2a_.w, 2, u1_);                          \
    PAIR(x1b_.x, x1b_.y, x2b_.x, x2b_.y, 4, u2_);                          \
    PAIR(x1b_.z, x1b_.w, x2b_.z, x2b_.w, 6, u3_);                          \
    u32x4 av_; av_.x = u0_; av_.y = u1_; av_.z = u2_; av_.w = u3_;         \
    Avar = __builtin_bit_cast(bf16x8, av_);                                \
} while (0)

#define MAKE_AFR(ch, abv, A0, A1, A2, A3) do {                             \
    MAKE_ONE(ch, 0, A0, abv.x);                                            \
    MAKE_ONE(ch, 1, A1, abv.y);                                            \
    MAKE_ONE(ch, 2, A2, abv.z);                                            \
    MAKE_ONE(ch, 3, A3, abv.w);                                            \
} while (0)

#define MFMA_KS(ct, ks, Af) do {                                           \
    const bf16x8 bb_ = *(const bf16x8*)(src_ + (ks) * 4096 +               \
                        ((ct) * 16 + m15) * 64 + slotoff);                 \
    acc##ct = __builtin_amdgcn_mfma_f32_16x16x32_bf16(Af, bb_, acc##ct,    \
                                                      0, 0, 0);            \
} while (0)

#define MFMA_CT(ct, A0, A1, A2, A3) do {                                   \
    MFMA_KS(ct, 0, A0); MFMA_KS(ct, 1, A1);                                \
    MFMA_KS(ct, 2, A2); MFMA_KS(ct, 3, A3);                                \
} while (0)

#define MFMA_CHUNK(ch, A0, A1, A2, A3) do {                                \
    const char* src_ = (const char*)sB[(ch) & 1];                          \
    MFMA_CT(0, A0, A1, A2, A3); MFMA_CT(1, A0, A1, A2, A3);                \
    MFMA_CT(2, A0, A1, A2, A3); MFMA_CT(3, A0, A1, A2, A3);                \
} while (0)

#define DMA(ch) do {                                                       \
    const unsigned short* dsrc_ = gBbt + (ch) * 8192 + w * 2048 + lane * 8;\
    unsigned short* ddst_ = &sB[(ch) & 1][w * 2048];                       \
    __builtin_amdgcn_global_load_lds(                                      \
        (const __attribute__((address_space(1))) unsigned int*)(dsrc_),    \
        (__attribute__((address_space(3))) unsigned int*)(ddst_), 16, 0, 0);\
    __builtin_amdgcn_global_load_lds(                                      \
        (const __attribute__((address_space(1))) unsigned int*)(dsrc_+512),\
        (__attribute__((address_space(3))) unsigned int*)(ddst_+512), 16, 0, 0);\
    __builtin_amdgcn_global_load_lds(                                      \
        (const __attribute__((address_space(1))) unsigned int*)(dsrc_+1024),\
        (__attribute__((address_space(3))) unsigned int*)(ddst_+1024), 16, 0, 0);\
    __builtin_amdgcn_global_load_lds(                                      \
        (const __attribute__((address_space(1))) unsigned int*)(dsrc_+1536),\
        (__attribute__((address_space(3))) unsigned int*)(ddst_+1536), 16, 0, 0);\
} while (0)

#define EPI(ct, accv) do {                                                 \
    float h0_ = accv.x * rinv0, h1_ = accv.y * rinv1,                      \
          h2_ = accv.z * rinv2, h3_ = accv.w * rinv3;                      \
    h0_ = (h0_ > 0.f) ? h0_ : (__expf(h0_) - 1.f);                         \
    h1_ = (h1_ > 0.f) ? h1_ : (__expf(h1_) - 1.f);                         \
    h2_ = (h2_ > 0.f) ? h2_ : (__expf(h2_) - 1.f);                         \
    h3_ = (h3_ > 0.f) ? h3_ : (__expf(h3_) - 1.f);                         \
    float* op_ = out + (size_t)(bt * N + i0 + w * 16 + q * 4) * F          \
                 + (ct) * 16 + m15;                                        \
    op_[0 * F] = h0_; op_[1 * F] = h1_; op_[2 * F] = h2_; op_[3 * F] = h3_;\
} while (0)

__global__ __launch_bounds__(256, 3) void k_attn(
    const unsigned int* __restrict__ adjBits,
    const unsigned short* __restrict__ WhSw,
    const float* __restrict__ s1, const float* __restrict__ s2,
    const float* __restrict__ f1v, const float* __restrict__ f2v,
    float* __restrict__ out)
{
    __shared__ __align__(16) float sX1[N];                  // 2^c   (scaled domain)
    __shared__ __align__(16) float sX2[N];                  // 2^.2c
    __shared__ __align__(16) unsigned short sB[2][8192];    // 2 x 16 KB
    __shared__ float sWmax[4];

    const int tid  = threadIdx.x;
    const int xcd = blockIdx.x & 7;                         // XCD swizzle: 6 bt/XCD
    const int idx = blockIdx.x >> 3;
    const int bt  = xcd * 6 + (idx >> 4);
    const int i0  = (idx & 15) * 64;
    const int lane = tid & 63;
    const int w    = tid >> 6;
    const int q    = lane >> 4;
    const int m15  = lane & 15;

    const int growq = i0 + w * 16 + m15;
    const unsigned int* abRow = adjBits + growq * 32;
    const uint4* abRow4 = (const uint4*)abRow;

    // HOIST all adjacency words into registers — keeps the chunk loop
    // free of VMEM so counted vmcnt is exact.
    const uint4 ab0 = abRow4[0], ab1 = abRow4[1], ab2 = abRow4[2], ab3 = abRow4[3];
    const uint4 ab4 = abRow4[4], ab5 = abRow4[5], ab6 = abRow4[6], ab7 = abRow4[7];
    const float rraw = s1[bt * N + growq] + f1v[growq];

    // stage X1/X2 and track block max of c (scaled by log2e)
    float cmax = -1e30f;
    for (int j = tid; j < N; j += 256) {
        const float c = (s2[bt * N + j] + f2v[j]) * L2E;
        sX1[j] = exp2f(c);
        sX2[j] = exp2f(LRELU_A * c);
        cmax = fmaxf(cmax, c);
    }
#pragma unroll
    for (int off = 32; off >= 1; off >>= 1) cmax = fmaxf(cmax, __shfl_xor(cmax, off, 64));
    if (lane == 0) sWmax[w] = cmax;
    __syncthreads();            // full drain once; clean slate for vmcnt counting
    const float mx = fmaxf(fmaxf(sWmax[0], sWmax[1]), fmaxf(sWmax[2], sWmax[3]));

    const float r    = rraw * L2E;                          // scaled domain
    const float smx  = r + mx;
    const float mhat = fmaxf(smx, LRELU_A * smx);           // >= every scaled e in row
    const float E1 = exp2f(r - mhat);
    const float E2 = exp2f(LRELU_A * r - mhat);
    float lsum = 0.f;

    const unsigned short* gBbt = WhSw + (size_t)bt * 65536;
    const int slotoff = ((q + m15) & 3) * 16;               // XOR-swizzled slot

    f32x4 acc0 = 0.f, acc1 = 0.f, acc2 = 0.f, acc3 = 0.f;
    bf16x8 fA0, fA1, fA2, fA3, fB0, fB1, fB2, fB3;

    // counted-vmcnt double-buffer pipeline (R7 structure, proven-equal)
    MAKE_AFR(0, ab0, fA0, fA1, fA2, fA3);
    DMA(0); DMA(1);

    WAIT_VM4; BAR;                                          // sB[0] ready
    MFMA_CHUNK(0, fA0, fA1, fA2, fA3); MAKE_AFR(1, ab1, fB0, fB1, fB2, fB3);
    BAR; DMA(2); WAIT_VM4; BAR;                             // sB[1] ready
    MFMA_CHUNK(1, fB0, fB1, fB2, fB3); MAKE_AFR(2, ab2, fA0, fA1, fA2, fA3);
    BAR; DMA(3); WAIT_VM4; BAR;
    MFMA_CHUNK(2, fA0, fA1, fA2, fA3); MAKE_AFR(3, ab3, fB0, fB1, fB2, fB3);
    BAR; DMA(4); WAIT_VM4; BAR;
    MFMA_CHUNK(3, fB0, fB1, fB2, fB3); MAKE_AFR(4, ab4, fA0, fA1, fA2, fA3);
    BAR; DMA(5); WAIT_VM4; BAR;
    MFMA_CHUNK(4, fA0, fA1, fA2, fA3); MAKE_AFR(5, ab5, fB0, fB1, fB2, fB3);
    BAR; DMA(6); WAIT_VM4; BAR;
    MFMA_CHUNK(5, fB0, fB1, fB2, fB3); MAKE_AFR(6, ab6, fA0, fA1, fA2, fA3);
    BAR; DMA(7); WAIT_VM4; BAR;
    MFMA_CHUNK(6, fA0, fA1, fA2, fA3); MAKE_AFR(7, ab7, fB0, fB1, fB2, fB3);
    WAIT_VM0; BAR;                                          // sB[1] (chunk 7) ready
    MFMA_CHUNK(7, fB0, fB1, fB2, fB3);

    // row denominators: lanes {l, l^16, l^32, l^48} share row m15
    lsum += __shfl_xor(lsum, 16, 64);
    lsum += __shfl_xor(lsum, 32, 64);

    const float rinv0 = 1.f / __shfl(lsum, q * 4 + 0, 64);
    const float rinv1 = 1.f / __shfl(lsum, q * 4 + 1, 64);
    const float rinv2 = 1.f / __shfl(lsum, q * 4 + 2, 64);
    const float rinv3 = 1.f / __shfl(lsum, q * 4 + 3, 64);

    EPI(0, acc0); EPI(1, acc1); EPI(2, acc2); EPI(3, acc3);
}

// ------------------------------------------------------------------
extern "C" void kernel_launch(void* const* d_in, const int* in_sizes, int n_in,
                              void* d_out, int out_size, void* d_ws, size_t ws_size,
                              hipStream_t stream)
{
    const float* x    = (const float*)d_in[0];
    const int*   adj  = (const int*)  d_in[1];
    const float* emb1 = (const float*)d_in[2];
    const float* emb2 = (const float*)d_in[3];
    const float* W    = (const float*)d_in[4];
    const float* a    = (const float*)d_in[5];
    const float* a2   = (const float*)d_in[6];
    float* out = (float*)d_out;

    unsigned short* WhSw = (unsigned short*)d_ws;             // 6.29 MB
    float* s1 = (float*)(WhSw + (size_t)BT * 65536);
    float* s2 = s1 + BT * N;
    float* f1 = s2 + BT * N;
    float* f2 = f1 + N;
    unsigned int* adjBits = (unsigned int*)(f2 + N);          // 128 KB

    hipLaunchKernelGGL(k_proj_misc, dim3(768), dim3(256), 0, stream,
                       x, W, a, adj, emb1, emb2, a2, WhSw, s1, s2, adjBits, f1, f2);
    hipLaunchKernelGGL(k_attn, dim3(BT * 16), dim3(256), 0, stream,
                       adjBits, WhSw, s1, s2, f1, f2, out);
}